// Round 5
// baseline (447.179 us; speedup 1.0000x reference)
//
#include <hip/hip_runtime.h>
#include <math.h>

#define N 1024
#define BATCH 16
#define CH 3
#define BC 48
#define OUTHW 224
#define KSCALE (1024.0f / 224.0f)
#define SCALE  (224.0f / 1024.0f)
#define ABYTES ((size_t)BC * N * N * 8)      // 384 MiB workspace (48 x 8 MB slabs)
#define T1OFF  (768 * 2048)                  // float offset of T1 inside each slab
#define SLOTOFF 1802240                      // slab-0 tail: after T1 (1572864+1024*224)
#define WBAR() __builtin_amdgcn_wave_barrier()

// (ar,ai)*(br,bi) -> (dr,di); safe when d aliases a
#define CMUL(dr, di, ar, ai, br, bi) do {                         \
    float _r = (ar) * (br) - (ai) * (bi);                         \
    float _i = (ar) * (bi) + (ai) * (br);                         \
    (dr) = _r; (di) = _i; } while (0)

// forward DFT-4
#define RADIX4(ar,ai,br,bi,cr,ci,dr,di, o0r,o0i,o1r,o1i,o2r,o2i,o3r,o3i) do { \
    float u0r=(ar)+(cr), u0i=(ai)+(ci);                           \
    float u1r=(ar)-(cr), u1i=(ai)-(ci);                           \
    float u2r=(br)+(dr), u2i=(bi)+(di);                           \
    float u3r=(bi)-(di), u3i=(dr)-(br);                           \
    (o0r)=u0r+u2r; (o0i)=u0i+u2i;                                 \
    (o1r)=u1r+u3r; (o1i)=u1i+u3i;                                 \
    (o2r)=u0r-u2r; (o2i)=u0i-u2i;                                 \
    (o3r)=u1r-u3r; (o3i)=u1i-u3i; } while (0)

// In-register natural-order 16-pt forward DFT (Stockham radix-4 x radix-4).
__device__ __forceinline__ void dft16(float* xr, float* xi) {
  const float W16R[4][4] = {
    {1.f, 1.f, 1.f, 1.f},
    {1.f,  0.9238795325f,  0.7071067812f,  0.3826834324f},
    {1.f,  0.7071067812f,  0.0f,          -0.7071067812f},
    {1.f,  0.3826834324f, -0.7071067812f, -0.9238795325f}};
  const float W16I[4][4] = {
    {0.f, 0.f, 0.f, 0.f},
    {0.f, -0.3826834324f, -0.7071067812f, -0.9238795325f},
    {0.f, -0.7071067812f, -1.0f,          -0.7071067812f},
    {0.f, -0.9238795325f, -0.7071067812f,  0.3826834324f}};
  float tr[16], ti[16];
#pragma unroll
  for (int j = 0; j < 4; ++j) {
    RADIX4(xr[j],xi[j], xr[j+4],xi[j+4], xr[j+8],xi[j+8], xr[j+12],xi[j+12],
           tr[4*j],ti[4*j], tr[4*j+1],ti[4*j+1], tr[4*j+2],ti[4*j+2], tr[4*j+3],ti[4*j+3]);
  }
#pragma unroll
  for (int j = 0; j < 4; ++j) {
    float ar[4], ai_[4];
#pragma unroll
    for (int k = 0; k < 4; ++k) {
      if (j == 0 || k == 0) { ar[k] = tr[j+4*k]; ai_[k] = ti[j+4*k]; }
      else CMUL(ar[k], ai_[k], tr[j+4*k], ti[j+4*k], W16R[j][k], W16I[j][k]);
    }
    RADIX4(ar[0],ai_[0], ar[1],ai_[1], ar[2],ai_[2], ar[3],ai_[3],
           xr[j],xi[j], xr[j+4],xi[j+4], xr[j+8],xi[j+8], xr[j+12],xi[j+12]);
  }
}

__device__ __forceinline__ void stage2(float* xr, float* xi,
                                       const float2* __restrict__ twg, int j2) {
#pragma unroll
  for (int k = 1; k < 16; ++k) {       // twiddle W256^{j2*k}
    float2 w = twg[4 * j2 * k];
    CMUL(xr[k], xi[k], xr[k], xi[k], w.x, w.y);
  }
  dft16(xr, xi);
}

// 1-buffer wave FFT (proven R4): sequential re/im round-trips through ONE
// 1088-float buffer (in-order DS pipe: re-loads drain before im-stores
// overwrite). Spill-free: the ex2 gather lands at slots xr[m+4k], making
// stage 3 an exact in-place butterfly (bins l+64m+256k -> slot m+4k).
__device__ __forceinline__ void wave_fft1024_1buf(float* xr, float* xi,
                                                  float* wb,
                                                  const float2* __restrict__ twg,
                                                  int l) {
  const int base2 = l + (l >> 4);
  const int j2 = l & 15;
  const int ob = 272 * (l >> 4) + j2;
  dft16(xr, xi);                       // stage 1 (Ns=1)
#pragma unroll
  for (int k = 0; k < 16; ++k) wb[17*l + k] = xr[k];
  WBAR();
#pragma unroll
  for (int k = 0; k < 16; ++k) xr[k] = wb[base2 + 68*k];
  WBAR();
#pragma unroll
  for (int k = 0; k < 16; ++k) wb[17*l + k] = xi[k];
  WBAR();
#pragma unroll
  for (int k = 0; k < 16; ++k) xi[k] = wb[base2 + 68*k];
  WBAR();
  stage2(xr, xi, twg, j2);             // stage 2 (Ns=16)
#pragma unroll
  for (int k = 0; k < 16; ++k) wb[ob + 17*k] = xr[k];
  WBAR();
#pragma unroll
  for (int m = 0; m < 4; ++m)
#pragma unroll
    for (int k = 0; k < 4; ++k) xr[m + 4*k] = wb[base2 + 68*m + 272*k];
  WBAR();
#pragma unroll
  for (int k = 0; k < 16; ++k) wb[ob + 17*k] = xi[k];
  WBAR();
#pragma unroll
  for (int m = 0; m < 4; ++m)
#pragma unroll
    for (int k = 0; k < 4; ++k) xi[m + 4*k] = wb[base2 + 68*m + 272*k];
  WBAR();
#pragma unroll
  for (int m = 0; m < 4; ++m) {        // stage 3 (Ns=256, radix-4), in-place
    float ar[4], ai_[4];
#pragma unroll
    for (int k = 0; k < 4; ++k) { ar[k] = xr[m + 4*k]; ai_[k] = xi[m + 4*k]; }
    const int j = l + 64*m;
#pragma unroll
    for (int k = 1; k < 4; ++k) {
      float2 w = twg[j * k];
      CMUL(ar[k], ai_[k], ar[k], ai_[k], w.x, w.y);
    }
    RADIX4(ar[0],ai_[0], ar[1],ai_[1], ar[2],ai_[2], ar[3],ai_[3],
           xr[m],xi[m], xr[m+4],xi[m+4], xr[m+8],xi[m+8], xr[m+12],xi[m+12]);
  }
}

__global__ void k_init(float2* __restrict__ tw, int* __restrict__ slots) {
  int g = blockIdx.x * 256 + threadIdx.x;   // 0..2047
  if (g < 1024) {
    float ang = -6.283185307179586f * ((float)g / 1024.0f);
    float s, c;
    sincosf(ang, &s, &c);
    tw[g] = make_float2(c, s);
    slots[g] = 0x7F800000;                  // +inf (min slots, 16 b x 64 slices)
  } else {
    slots[g] = 0;                           // 0 (max slots; spec >= 0)
  }
}

// Reduce 64 slices per image -> mnmx[32].
__global__ void k_reduce(const int* __restrict__ slots, int* __restrict__ mnmx) {
  const int t = threadIdx.x;
  const int b = t >> 6, s = t & 63;
  int mn = slots[b * 64 + s];
  int mx = slots[1024 + b * 64 + s];
#pragma unroll
  for (int off = 32; off; off >>= 1) {
    mn = min(mn, __shfl_xor(mn, off));
    mx = max(mx, __shfl_xor(mx, off));
  }
  if (s == 0) { mnmx[b] = mn; mnmx[BATCH + b] = mx; }
}

// Pass 1: packed row-pair FFT (1-buffer -> 17408 B/block), Hermitian unpack
// via sequential re/im partner exchange, then transposed float2 write in TWO
// half-rounds over v (stage 8x260 re + 8x260 im = 4160 floats <= 4352).
// A layout unchanged (float2 A^T[v][h]); k_colfft untouched.
__global__ __launch_bounds__(256, 6) void k_rowfft(const float* __restrict__ in,
                                                   float2* __restrict__ A,
                                                   const float2* __restrict__ twg) {
  __shared__ float lds[4352];          // 4 waves x 1088; reused as 2x8x260 staging
  const int t  = threadIdx.x;
  const int w  = t >> 6;
  const int l  = t & 63;
  const int bc  = blockIdx.x >> 7;
  const int h0b = (blockIdx.x & 127) << 3;
  const int r0  = h0b + 2 * w;
  float* wb = lds + w * 1088;
  const float* row0 = in + ((size_t)bc << 20) + ((size_t)r0 << 10);
  const float* row1 = row0 + N;
  float xr[16], xi[16];
  const float sgn = (l & 1) ? -1.0f : 1.0f;   // fftshift sign (-1)^h
#pragma unroll
  for (int k = 0; k < 16; ++k) {
    xr[k] =  sgn * row0[l + 64*k];
    xi[k] = -sgn * row1[l + 64*k];
  }
  wave_fft1024_1buf(xr, xi, wb, twg, l);
  // Hermitian unpack: A=(P+conj(Q))/2, B=-i(P-conj(Q))/2, Q=Z[(N-i)&1023]
  // re round (qr -> arr, bri), then im round (qi -> ari, brr); in-order DS
  // pipe lets the im-stores safely follow the re-loads in one buffer.
  float arr[9], ari[9], brr[9], bri[9];
#pragma unroll
  for (int s = 0; s < 16; ++s) wb[l + 64*s] = xr[s];
  WBAR();
#pragma unroll
  for (int s = 0; s < 9; ++s) {
    int nk = (N - (l + 64*s)) & (N - 1);
    float qr = wb[nk];
    arr[s] = 0.5f * (xr[s] + qr);
    bri[s] = 0.5f * (qr - xr[s]);
  }
  WBAR();
#pragma unroll
  for (int s = 0; s < 16; ++s) wb[l + 64*s] = xi[s];
  WBAR();
#pragma unroll
  for (int s = 0; s < 9; ++s) {
    int nk = (N - (l + 64*s)) & (N - 1);
    float qi = wb[nk];
    ari[s] = 0.5f * (xi[s] - qi);
    brr[s] = 0.5f * (xi[s] + qi);
  }
  // Transposed write, two half-rounds over v. stre/stim rows: 2w (A), 2w+1 (B).
  float* stre = lds;                   // [8][260]
  float* stim = lds + 2080;            // [8][260]
  const int rr = t & 7, v0 = t >> 3;
  float2* Abc = A + ((size_t)bc << 20);
  __syncthreads();                     // staging overlays all wave wb buffers
  // ---- half 0: v in [0,256)  (s = 0..3, i = l+64s < 256 always)
#pragma unroll
  for (int s = 0; s < 4; ++s) {
    int i = l + 64*s;
    stre[(2*w)     * 260 + i] = arr[s]; stim[(2*w)     * 260 + i] = ari[s];
    stre[(2*w + 1) * 260 + i] = brr[s]; stim[(2*w + 1) * 260 + i] = bri[s];
  }
  __syncthreads();
#pragma unroll
  for (int i2 = 0; i2 < 8; ++i2) {
    int v = v0 + 32 * i2;              // covers 0..255 exactly
    Abc[(size_t)v * N + h0b + rr] = make_float2(stre[rr*260 + v], stim[rr*260 + v]);
  }
  __syncthreads();
  // ---- half 1: v in [256,512]  (s = 4..8, i <= 512)
#pragma unroll
  for (int s = 4; s < 9; ++s) {
    int i = l + 64*s;
    if (i <= 512) {
      int c = i - 256;
      stre[(2*w)     * 260 + c] = arr[s]; stim[(2*w)     * 260 + c] = ari[s];
      stre[(2*w + 1) * 260 + c] = brr[s]; stim[(2*w + 1) * 260 + c] = bri[s];
    }
  }
  __syncthreads();
#pragma unroll
  for (int i2 = 0; i2 < 9; ++i2) {
    int v = 256 + v0 + 32 * i2;        // covers 256..512 (+bound)
    if (v <= 512) {
      int c = v - 256;
      Abc[(size_t)v * N + h0b + rr] = make_float2(stre[rr*260 + c], stim[rr*260 + c]);
    }
  }
}

// Pass 2 (verbatim R4): fused column FFT (1-buffer, 17408 B/block) + spec +
// sliced minmax atomics + 10-tap fused resize for column sx and mirror N-sx.
__global__ __launch_bounds__(256, 8) void k_colfft(const float2* __restrict__ A,
                                                   float* __restrict__ WSf,
                                                   int* __restrict__ slots,
                                                   const float2* __restrict__ twg) {
  __shared__ float lds[4352];          // 4 waves x 1088
  const int t  = threadIdx.x;
  const int w  = t >> 6;
  const int l  = t & 63;
  const int gw = blockIdx.x * 4 + w;   // 0..24623 == BC*513-1 exactly
  const int bc = gw / 513;
  const int sx = gw - bc * 513;
  const int b  = bc / CH;
  float* wb = lds + w * 1088;
  const float2* src = A + ((size_t)bc << 20) + ((size_t)sx << 10);
  float xr[16], xi[16];
#pragma unroll
  for (int k = 0; k < 16; ++k) { float2 v = src[l + 64*k]; xr[k] = v.x; xi[k] = v.y; }
  wave_fft1024_1buf(xr, xi, wb, twg, l);
  float lmin = 3.4e38f, lmax = 0.0f;
#pragma unroll
  for (int s = 0; s < 16; ++s) {
    float sp = __logf(1.0f + sqrtf(xr[s]*xr[s] + xi[s]*xi[s]));
    wb[l + 64*s] = sp;                 // spec plain-indexed in own buffer
    lmin = fminf(lmin, sp); lmax = fmaxf(lmax, sp);
  }
#pragma unroll
  for (int off = 32; off; off >>= 1) {
    lmin = fminf(lmin, __shfl_xor(lmin, off));
    lmax = fmaxf(lmax, __shfl_xor(lmax, off));
  }
  if (l == 0) {                        // spread over 64 slices/image
    atomicMin(&slots[b * 64 + (sx & 63)],        __float_as_int(lmin));
    atomicMax(&slots[1024 + b * 64 + (sx & 63)], __float_as_int(lmax));
  }
  WBAR();
  float* T1 = WSf + ((size_t)bc << 21) + T1OFF;
  const bool mir = (sx != 0) && (sx != 512);
#pragma unroll
  for (int obk = 0; obk < 4; ++obk) {
    int oh = l + 64 * obk;
    if (oh < OUTHW) {
      float x = ((float)oh + 0.5f) * KSCALE - 0.5f;
      int jlo = (int)ceilf(x - KSCALE);           // unclamped; window < 10 taps
      float ssum = 0.0f, acc = 0.0f, accm = 0.0f;
#pragma unroll
      for (int u = 0; u < 10; ++u) {
        int j = jlo + u;
        float wgt = 1.0f - fabsf((float)j - x) * SCALE;
        wgt = fmaxf(wgt, 0.0f);
        bool valid = (j >= 0) && (j <= N - 1);
        if (!valid) wgt = 0.0f;
        int ja = valid ? j : 0;
        ssum += wgt;
        acc  += wgt * wb[ja];
        accm += wgt * wb[(N - ja) & (N - 1)];
      }
      float inv = 1.0f / ssum;
      T1[(size_t)sx * OUTHW + oh] = acc * inv;
      if (mir) T1[(size_t)(N - sx) * OUTHW + oh] = accm * inv;
    }
  }
}

// Pass 3 (verbatim R4): contract v + normalization; fixed 10-tap inner loop.
__global__ __launch_bounds__(256) void k_resize2(const float2* __restrict__ A,
                                                 const int* __restrict__ mnmx,
                                                 float* __restrict__ out) {
  __shared__ float win[11 * OUTHW];
  const int ow = blockIdx.x % OUTHW;
  const int bc = blockIdx.x / OUTHW;
  const int b  = bc / CH;
  const int t  = threadIdx.x;
  const float* T1 = (const float*)(A + ((size_t)bc << 20)) + T1OFF;
  float x = ((float)ow + 0.5f) * KSCALE - 0.5f;
  int jlo_u = (int)ceilf(x - KSCALE);            // unclamped
  int jlo = jlo_u < 0 ? 0 : jlo_u;
  int jhi = (int)floorf(x + KSCALE); if (jhi > N - 1) jhi = N - 1;
  const int nel = (jhi - jlo + 1) * OUTHW;
  const float* src = T1 + (size_t)jlo * OUTHW;
  for (int e = t; e < nel; e += 256) win[e] = src[e];
  __syncthreads();
  const float mn = __int_as_float(mnmx[b]);
  const float mx = __int_as_float(mnmx[BATCH + b]);
  const float inv = 1.0f / (mx - mn + 1e-8f);
  if (t < OUTHW) {
    float ssum = 0.0f, acc = 0.0f;
#pragma unroll
    for (int u = 0; u < 10; ++u) {
      int j = jlo_u + u;
      float wv = 1.0f - fabsf((float)j - x) * SCALE;
      wv = fmaxf(wv, 0.0f);
      bool valid = (j >= 0) && (j <= N - 1);
      if (!valid) wv = 0.0f;
      int ja = (valid && wv > 0.0f) ? (j - jlo) : 0;
      ssum += wv;
      acc += wv * win[ja * OUTHW + t];
    }
    float v = acc / ssum;
    out[((size_t)bc * OUTHW + t) * OUTHW + ow] = (v - mn) * inv;
  }
}

extern "C" void kernel_launch(void* const* d_in, const int* in_sizes, int n_in,
                              void* d_out, int out_size, void* d_ws, size_t ws_size,
                              hipStream_t stream) {
  const float* in = (const float*)d_in[0];
  float* out = (float*)d_out;
  float2* A = (float2*)d_ws;
  float* WSf = (float*)d_ws;
  int* mnmx = (int*)((char*)d_ws + ABYTES);
  float2* twg = (float2*)((char*)d_ws + ABYTES + 128);
  int* slots = (int*)(WSf + SLOTOFF);          // slab-0 tail, after T1

  k_init<<<8, 256, 0, stream>>>(twg, slots);
  k_rowfft<<<BC * 128, 256, 0, stream>>>(in, A, twg);
  k_colfft<<<(BC * 513) / 4, 256, 0, stream>>>(A, WSf, slots, twg);
  k_reduce<<<1, 1024, 0, stream>>>(slots, mnmx);
  k_resize2<<<BC * OUTHW, 256, 0, stream>>>(A, mnmx, out);
}

// Round 6
// 431.231 us; speedup vs baseline: 1.0370x; 1.0370x over previous
//
#include <hip/hip_runtime.h>
#include <math.h>

#define N 1024
#define BATCH 16
#define CH 3
#define BC 48
#define OUTHW 224
#define KSCALE (1024.0f / 224.0f)
#define SCALE  (224.0f / 1024.0f)
#define ABYTES ((size_t)BC * N * N * 8)      // 384 MiB workspace (48 x 8 MB slabs)
#define T1OFF  (768 * 2048)                  // float offset of T1 inside each slab
#define SLOTOFF 1802240                      // slab-0 tail: after T1 (1572864+1024*224)
#define WBAR() __builtin_amdgcn_wave_barrier()

// (ar,ai)*(br,bi) -> (dr,di); safe when d aliases a
#define CMUL(dr, di, ar, ai, br, bi) do {                         \
    float _r = (ar) * (br) - (ai) * (bi);                         \
    float _i = (ar) * (bi) + (ai) * (br);                         \
    (dr) = _r; (di) = _i; } while (0)

// forward DFT-4
#define RADIX4(ar,ai,br,bi,cr,ci,dr,di, o0r,o0i,o1r,o1i,o2r,o2i,o3r,o3i) do { \
    float u0r=(ar)+(cr), u0i=(ai)+(ci);                           \
    float u1r=(ar)-(cr), u1i=(ai)-(ci);                           \
    float u2r=(br)+(dr), u2i=(bi)+(di);                           \
    float u3r=(bi)-(di), u3i=(dr)-(br);                           \
    (o0r)=u0r+u2r; (o0i)=u0i+u2i;                                 \
    (o1r)=u1r+u3r; (o1i)=u1i+u3i;                                 \
    (o2r)=u0r-u2r; (o2i)=u0i-u2i;                                 \
    (o3r)=u1r-u3r; (o3i)=u1i-u3i; } while (0)

// In-register natural-order 16-pt forward DFT (Stockham radix-4 x radix-4).
__device__ __forceinline__ void dft16(float* xr, float* xi) {
  const float W16R[4][4] = {
    {1.f, 1.f, 1.f, 1.f},
    {1.f,  0.9238795325f,  0.7071067812f,  0.3826834324f},
    {1.f,  0.7071067812f,  0.0f,          -0.7071067812f},
    {1.f,  0.3826834324f, -0.7071067812f, -0.9238795325f}};
  const float W16I[4][4] = {
    {0.f, 0.f, 0.f, 0.f},
    {0.f, -0.3826834324f, -0.7071067812f, -0.9238795325f},
    {0.f, -0.7071067812f, -1.0f,          -0.7071067812f},
    {0.f, -0.9238795325f, -0.7071067812f,  0.3826834324f}};
  float tr[16], ti[16];
#pragma unroll
  for (int j = 0; j < 4; ++j) {
    RADIX4(xr[j],xi[j], xr[j+4],xi[j+4], xr[j+8],xi[j+8], xr[j+12],xi[j+12],
           tr[4*j],ti[4*j], tr[4*j+1],ti[4*j+1], tr[4*j+2],ti[4*j+2], tr[4*j+3],ti[4*j+3]);
  }
#pragma unroll
  for (int j = 0; j < 4; ++j) {
    float ar[4], ai_[4];
#pragma unroll
    for (int k = 0; k < 4; ++k) {
      if (j == 0 || k == 0) { ar[k] = tr[j+4*k]; ai_[k] = ti[j+4*k]; }
      else CMUL(ar[k], ai_[k], tr[j+4*k], ti[j+4*k], W16R[j][k], W16I[j][k]);
    }
    RADIX4(ar[0],ai_[0], ar[1],ai_[1], ar[2],ai_[2], ar[3],ai_[3],
           xr[j],xi[j], xr[j+4],xi[j+4], xr[j+8],xi[j+8], xr[j+12],xi[j+12]);
  }
}

__device__ __forceinline__ void stage2(float* xr, float* xi,
                                       const float2* __restrict__ twg, int j2) {
#pragma unroll
  for (int k = 1; k < 16; ++k) {       // twiddle W256^{j2*k}
    float2 w = twg[4 * j2 * k];
    CMUL(xr[k], xi[k], xr[k], xi[k], w.x, w.y);
  }
  dft16(xr, xi);
}

// 2-buffer wave FFT (R0/R4-proven; 52-VGPR class — used by k_rowfft whose
// Hermitian-unpack phase needs the register headroom: R5 showed the 1-buffer
// variant compiles rowfft to 36 VGPR = scratch spills, canceling occupancy).
__device__ __forceinline__ void wave_fft1024(float* xr, float* xi,
                                             float* sre, float* sim,
                                             const float2* __restrict__ twg, int l) {
  dft16(xr, xi);
#pragma unroll
  for (int k = 0; k < 16; ++k) { sre[17*l + k] = xr[k]; sim[17*l + k] = xi[k]; }
  WBAR();
  const int base2 = l + (l >> 4);
#pragma unroll
  for (int k = 0; k < 16; ++k) { xr[k] = sre[base2 + 68*k]; xi[k] = sim[base2 + 68*k]; }
  const int j2 = l & 15;
  stage2(xr, xi, twg, j2);
  const int ob = 272 * (l >> 4) + j2;
#pragma unroll
  for (int k = 0; k < 16; ++k) { sre[ob + 17*k] = xr[k]; sim[ob + 17*k] = xi[k]; }
  WBAR();
#pragma unroll
  for (int m = 0; m < 4; ++m) {
    float ar[4], ai_[4];
#pragma unroll
    for (int k = 0; k < 4; ++k) {
      ar[k] = sre[base2 + 68*m + 272*k];
      ai_[k] = sim[base2 + 68*m + 272*k];
    }
    const int j = l + 64*m;
#pragma unroll
    for (int k = 1; k < 4; ++k) {
      float2 w = twg[j * k];
      CMUL(ar[k], ai_[k], ar[k], ai_[k], w.x, w.y);
    }
    RADIX4(ar[0],ai_[0], ar[1],ai_[1], ar[2],ai_[2], ar[3],ai_[3],
           xr[m],xi[m], xr[m+4],xi[m+4], xr[m+8],xi[m+8], xr[m+12],xi[m+12]);
  }
}

// 1-buffer wave FFT (R4-proven in colfft): sequential re/im round-trips through
// ONE 1088-float buffer (in-order DS pipe). Spill-free here: ex2 gather lands
// at slots xr[m+4k], making stage 3 an exact in-place butterfly.
__device__ __forceinline__ void wave_fft1024_1buf(float* xr, float* xi,
                                                  float* wb,
                                                  const float2* __restrict__ twg,
                                                  int l) {
  const int base2 = l + (l >> 4);
  const int j2 = l & 15;
  const int ob = 272 * (l >> 4) + j2;
  dft16(xr, xi);                       // stage 1 (Ns=1)
#pragma unroll
  for (int k = 0; k < 16; ++k) wb[17*l + k] = xr[k];
  WBAR();
#pragma unroll
  for (int k = 0; k < 16; ++k) xr[k] = wb[base2 + 68*k];
  WBAR();
#pragma unroll
  for (int k = 0; k < 16; ++k) wb[17*l + k] = xi[k];
  WBAR();
#pragma unroll
  for (int k = 0; k < 16; ++k) xi[k] = wb[base2 + 68*k];
  WBAR();
  stage2(xr, xi, twg, j2);             // stage 2 (Ns=16)
#pragma unroll
  for (int k = 0; k < 16; ++k) wb[ob + 17*k] = xr[k];
  WBAR();
#pragma unroll
  for (int m = 0; m < 4; ++m)
#pragma unroll
    for (int k = 0; k < 4; ++k) xr[m + 4*k] = wb[base2 + 68*m + 272*k];
  WBAR();
#pragma unroll
  for (int k = 0; k < 16; ++k) wb[ob + 17*k] = xi[k];
  WBAR();
#pragma unroll
  for (int m = 0; m < 4; ++m)
#pragma unroll
    for (int k = 0; k < 4; ++k) xi[m + 4*k] = wb[base2 + 68*m + 272*k];
  WBAR();
#pragma unroll
  for (int m = 0; m < 4; ++m) {        // stage 3 (Ns=256, radix-4), in-place
    float ar[4], ai_[4];
#pragma unroll
    for (int k = 0; k < 4; ++k) { ar[k] = xr[m + 4*k]; ai_[k] = xi[m + 4*k]; }
    const int j = l + 64*m;
#pragma unroll
    for (int k = 1; k < 4; ++k) {
      float2 w = twg[j * k];
      CMUL(ar[k], ai_[k], ar[k], ai_[k], w.x, w.y);
    }
    RADIX4(ar[0],ai_[0], ar[1],ai_[1], ar[2],ai_[2], ar[3],ai_[3],
           xr[m],xi[m], xr[m+4],xi[m+4], xr[m+8],xi[m+8], xr[m+12],xi[m+12]);
  }
}

__global__ void k_init(float2* __restrict__ tw, int* __restrict__ slots) {
  int g = blockIdx.x * 256 + threadIdx.x;   // 0..2047
  if (g < 1024) {
    float ang = -6.283185307179586f * ((float)g / 1024.0f);
    float s, c;
    sincosf(ang, &s, &c);
    tw[g] = make_float2(c, s);
    slots[g] = 0x7F800000;                  // +inf (min slots, 16 b x 64 slices)
  } else {
    slots[g] = 0;                           // 0 (max slots; spec >= 0)
  }
}

// Pass 1 (R4-exact): packed row-pair FFT (2-buffer), Hermitian unpack,
// block-staged transposed 64B-chunk write -> A^T[v][h].
__global__ __launch_bounds__(256, 4) void k_rowfft(const float* __restrict__ in,
                                                   float2* __restrict__ A,
                                                   const float2* __restrict__ twg) {
  __shared__ float lds[8704];
  const int t  = threadIdx.x;
  const int w  = t >> 6;
  const int l  = t & 63;
  const int bc  = blockIdx.x >> 7;
  const int h0b = (blockIdx.x & 127) << 3;
  const int r0  = h0b + 2 * w;
  float* sre = lds + w * 2176;
  float* sim = sre + 1088;
  const float* row0 = in + ((size_t)bc << 20) + ((size_t)r0 << 10);
  const float* row1 = row0 + N;
  float xr[16], xi[16];
  const float sgn = (l & 1) ? -1.0f : 1.0f;
#pragma unroll
  for (int k = 0; k < 16; ++k) {
    xr[k] =  sgn * row0[l + 64*k];
    xi[k] = -sgn * row1[l + 64*k];
  }
  wave_fft1024(xr, xi, sre, sim, twg, l);
#pragma unroll
  for (int s = 0; s < 16; ++s) { sre[l + 64*s] = xr[s]; sim[l + 64*s] = xi[s]; }
  WBAR();
  float arr[9], ari[9], brr[9], bri[9];
#pragma unroll
  for (int s = 0; s < 9; ++s) {
    int i  = l + 64*s;
    int nk = (N - i) & (N - 1);
    float pr = xr[s], pi = xi[s];
    float qr = sre[nk], qi = sim[nk];
    arr[s] = 0.5f * (pr + qr); ari[s] = 0.5f * (pi - qi);
    brr[s] = 0.5f * (pi + qi); bri[s] = 0.5f * (qr - pr);
  }
  __syncthreads();
  float* stre = lds;
  float* stim = lds + 4160;
#pragma unroll
  for (int s = 0; s < 9; ++s) {
    int i = l + 64*s;
    if (i <= 512) {
      stre[(2*w)     * 520 + i] = arr[s]; stim[(2*w)     * 520 + i] = ari[s];
      stre[(2*w + 1) * 520 + i] = brr[s]; stim[(2*w + 1) * 520 + i] = bri[s];
    }
  }
  __syncthreads();
  const int rr = t & 7, v0 = t >> 3;
  float2* Abc = A + ((size_t)bc << 20);
#pragma unroll
  for (int i2 = 0; i2 < 17; ++i2) {
    int v = v0 + 32 * i2;
    if (v <= 512) {
      Abc[(size_t)v * N + h0b + rr] = make_float2(stre[rr*520 + v], stim[rr*520 + v]);
    }
  }
}

// Pass 2 (R4-exact): fused column FFT (1-buffer, 17408 B/block -> 32 waves/CU)
// + spec + sliced minmax atomics + 10-tap fused resize (column sx, mirror N-sx).
__global__ __launch_bounds__(256, 8) void k_colfft(const float2* __restrict__ A,
                                                   float* __restrict__ WSf,
                                                   int* __restrict__ slots,
                                                   const float2* __restrict__ twg) {
  __shared__ float lds[4352];          // 4 waves x 1088
  const int t  = threadIdx.x;
  const int w  = t >> 6;
  const int l  = t & 63;
  const int gw = blockIdx.x * 4 + w;   // 0..24623 == BC*513-1 exactly
  const int bc = gw / 513;
  const int sx = gw - bc * 513;
  const int b  = bc / CH;
  float* wb = lds + w * 1088;
  const float2* src = A + ((size_t)bc << 20) + ((size_t)sx << 10);
  float xr[16], xi[16];
#pragma unroll
  for (int k = 0; k < 16; ++k) { float2 v = src[l + 64*k]; xr[k] = v.x; xi[k] = v.y; }
  wave_fft1024_1buf(xr, xi, wb, twg, l);
  float lmin = 3.4e38f, lmax = 0.0f;
#pragma unroll
  for (int s = 0; s < 16; ++s) {
    float sp = __logf(1.0f + sqrtf(xr[s]*xr[s] + xi[s]*xi[s]));
    wb[l + 64*s] = sp;                 // spec plain-indexed in own buffer
    lmin = fminf(lmin, sp); lmax = fmaxf(lmax, sp);
  }
#pragma unroll
  for (int off = 32; off; off >>= 1) {
    lmin = fminf(lmin, __shfl_xor(lmin, off));
    lmax = fmaxf(lmax, __shfl_xor(lmax, off));
  }
  if (l == 0) {                        // spread over 64 slices/image
    atomicMin(&slots[b * 64 + (sx & 63)],        __float_as_int(lmin));
    atomicMax(&slots[1024 + b * 64 + (sx & 63)], __float_as_int(lmax));
  }
  WBAR();
  float* T1 = WSf + ((size_t)bc << 21) + T1OFF;
  const bool mir = (sx != 0) && (sx != 512);
#pragma unroll
  for (int obk = 0; obk < 4; ++obk) {
    int oh = l + 64 * obk;
    if (oh < OUTHW) {
      float x = ((float)oh + 0.5f) * KSCALE - 0.5f;
      int jlo = (int)ceilf(x - KSCALE);           // unclamped; window < 10 taps
      float ssum = 0.0f, acc = 0.0f, accm = 0.0f;
#pragma unroll
      for (int u = 0; u < 10; ++u) {
        int j = jlo + u;
        float wgt = 1.0f - fabsf((float)j - x) * SCALE;
        wgt = fmaxf(wgt, 0.0f);
        bool valid = (j >= 0) && (j <= N - 1);
        if (!valid) wgt = 0.0f;
        int ja = valid ? j : 0;
        ssum += wgt;
        acc  += wgt * wb[ja];
        accm += wgt * wb[(N - ja) & (N - 1)];
      }
      float inv = 1.0f / ssum;
      T1[(size_t)sx * OUTHW + oh] = acc * inv;
      if (mir) T1[(size_t)(N - sx) * OUTHW + oh] = accm * inv;
    }
  }
}

// Pass 3: contract v + normalization. Direct coalesced T1 reads (no LDS window
// staging — T1 is L2/L3-resident and each tap row is an 896B coalesced read),
// fixed 10-tap unrolled loop, slot min/max reduction merged in (k_reduce gone).
__global__ __launch_bounds__(256) void k_resize2(const float2* __restrict__ A,
                                                 const int* __restrict__ slots,
                                                 float* __restrict__ out) {
  __shared__ float s2[2];
  const int ow = blockIdx.x % OUTHW;
  const int bc = blockIdx.x / OUTHW;
  const int b  = bc / CH;
  const int t  = threadIdx.x;
  // merged slot reduction: wave 0 -> min, wave 1 -> max (slots are bit
  // patterns of non-negative floats, so integer min/max is order-correct)
  if (t < 64) {
    int mn = slots[b * 64 + t];
#pragma unroll
    for (int off = 32; off; off >>= 1) mn = min(mn, __shfl_xor(mn, off));
    if (t == 0) s2[0] = __int_as_float(mn);
  } else if (t < 128) {
    int mx = slots[1024 + b * 64 + (t - 64)];
#pragma unroll
    for (int off = 32; off; off >>= 1) mx = max(mx, __shfl_xor(mx, off));
    if (t == 64) s2[1] = __int_as_float(mx);
  }
  __syncthreads();
  if (t >= OUTHW) return;
  const float mn = s2[0];
  const float mx = s2[1];
  const float inv = 1.0f / (mx - mn + 1e-8f);
  const float* T1 = (const float*)(A + ((size_t)bc << 20)) + T1OFF;
  float x = ((float)ow + 0.5f) * KSCALE - 0.5f;
  int jlo = (int)ceilf(x - KSCALE);              // unclamped; window < 10 taps
  float ssum = 0.0f, acc = 0.0f;
#pragma unroll
  for (int u = 0; u < 10; ++u) {
    int j = jlo + u;
    float wv = 1.0f - fabsf((float)j - x) * SCALE;
    wv = fmaxf(wv, 0.0f);
    bool valid = (j >= 0) && (j <= N - 1);
    if (!valid) wv = 0.0f;
    int ja = valid ? j : 0;                      // row 0 always valid memory
    ssum += wv;
    acc += wv * T1[(size_t)ja * OUTHW + t];      // coalesced 896B per tap row
  }
  float v = acc / ssum;
  out[((size_t)bc * OUTHW + t) * OUTHW + ow] = (v - mn) * inv;
}

extern "C" void kernel_launch(void* const* d_in, const int* in_sizes, int n_in,
                              void* d_out, int out_size, void* d_ws, size_t ws_size,
                              hipStream_t stream) {
  const float* in = (const float*)d_in[0];
  float* out = (float*)d_out;
  float2* A = (float2*)d_ws;
  float* WSf = (float*)d_ws;
  float2* twg = (float2*)((char*)d_ws + ABYTES + 128);
  int* slots = (int*)(WSf + SLOTOFF);          // slab-0 tail, after T1

  k_init<<<8, 256, 0, stream>>>(twg, slots);
  k_rowfft<<<BC * 128, 256, 0, stream>>>(in, A, twg);
  k_colfft<<<(BC * 513) / 4, 256, 0, stream>>>(A, WSf, slots, twg);
  k_resize2<<<BC * OUTHW, 256, 0, stream>>>(A, slots, out);
}